// Round 8
// baseline (746.902 us; speedup 1.0000x reference)
//
#include <hip/hip_runtime.h>

// DecoderLSTM R8: unit-partitioned persistent kernel.
// 256 blocks = 64 ped-groups x 4 unit-groups. Block: 128 peds x 64 units.
// Exchange: 16B global_{load,store}_dwordx4 sc0 sc1 batched asm, in-asm
// s_waitcnt. fp32 LN2 partial-stats exchanged (folded into the same batch
// as partner-h: ONE drain). No local LN2 recompute. Own h staged pre-barrier.

typedef float  f32x4  __attribute__((ext_vector_type(4)));
typedef short  short8 __attribute__((ext_vector_type(8)));
typedef __bf16 bf16x8 __attribute__((ext_vector_type(8)));
typedef int    i32x4  __attribute__((ext_vector_type(4)));

#define WS_W     0                      // 640 KB
#define WS_HBUF  (640 * 1024)           // 8 MB: [2][64pg][8Tl][8kc][64] i32x4
#define WS_SBUF  (WS_HBUF + 8388608)    // 1 MB: [2][64pg][4ug][128] i32x4
#define WS_BIAS  (WS_SBUF + 1048576)    // 4 KB
#define WS_SCAL  (WS_BIAS + 4096)       // 64 B
#define WS_CTR   (WS_SCAL + 64)         // 64 * 256 B

__device__ __forceinline__ unsigned short f2bf(float f) {
  unsigned int u = __float_as_uint(f);
  u += 0x7FFFu + ((u >> 16) & 1u);  // RNE
  return (unsigned short)(u >> 16);
}
__device__ __forceinline__ float sigm(float x) {
  return __builtin_amdgcn_rcpf(1.0f + __expf(-x));
}
__device__ __forceinline__ float tanh_(float x) {
  float ax = fabsf(x);
  float t = __expf(-2.0f * ax);
  float r = (1.0f - t) * __builtin_amdgcn_rcpf(1.0f + t);
  return x >= 0.0f ? r : -r;
}
__device__ __forceinline__ f32x4 mfma16(short8 a, short8 b, f32x4 c) {
  return __builtin_amdgcn_mfma_f32_16x16x32_bf16(
      __builtin_bit_cast(bf16x8, a), __builtin_bit_cast(bf16x8, b), c, 0, 0, 0);
}
__device__ __forceinline__ void sc_store16(void* p, i32x4 v) {
  asm volatile("global_store_dwordx4 %0, %1, off sc0 sc1" ::"v"(p), "v"(v)
               : "memory");
}
__device__ __forceinline__ void drain_vm() {
  asm volatile("s_waitcnt vmcnt(0)" ::: "memory");
}
// 7 coherent 16B loads, all results valid at asm exit (waitcnt inside).
__device__ __forceinline__ void batch_load7(
    const i32x4* p0, const i32x4* p1, const i32x4* p2, const i32x4* p3,
    const i32x4* p4, const i32x4* p5, const i32x4* p6, i32x4& r0, i32x4& r1,
    i32x4& r2, i32x4& r3, i32x4& r4, i32x4& r5, i32x4& r6) {
  asm volatile(
      "global_load_dwordx4 %0, %7, off sc0 sc1\n\t"
      "global_load_dwordx4 %1, %8, off sc0 sc1\n\t"
      "global_load_dwordx4 %2, %9, off sc0 sc1\n\t"
      "global_load_dwordx4 %3, %10, off sc0 sc1\n\t"
      "global_load_dwordx4 %4, %11, off sc0 sc1\n\t"
      "global_load_dwordx4 %5, %12, off sc0 sc1\n\t"
      "global_load_dwordx4 %6, %13, off sc0 sc1\n\t"
      "s_waitcnt vmcnt(0)"
      : "=&v"(r0), "=&v"(r1), "=&v"(r2), "=&v"(r3), "=&v"(r4), "=&v"(r5),
        "=&v"(r6)
      : "v"(p0), "v"(p1), "v"(p2), "v"(p3), "v"(p4), "v"(p5), "v"(p6)
      : "memory");
}

// ---- Prologue 1: weights -> B-frag bf16, flat ((ug*10+kc)*16+g*4+uw)*512 ----
extern "C" __global__ void shuffle_weights(const float* __restrict__ Wih,
                                           const float* __restrict__ Whh,
                                           unsigned short* __restrict__ ws_w) {
  int t = blockIdx.x * 256 + threadIdx.x;  // 0..40959
  if (t >= 40960) return;
  int l = t & 63;
  int x = t >> 6;
  int uw = x & 3;
  int g = (x >> 2) & 3;
  int y = x >> 4;  // ug*10 + kc
  int kc = y % 10;
  int ug = y / 10;
  int row = g * 256 + ug * 64 + uw * 16 + (l & 15);
  unsigned short* dst = ws_w + (size_t)t * 8;
  if (kc < 2) {
    const float* src = Wih + row * 64 + kc * 32 + (l >> 4) * 8;
#pragma unroll
    for (int j = 0; j < 8; j++) dst[j] = f2bf(src[j]);
  } else {
    const float* src = Whh + row * 256 + (kc - 2) * 32 + (l >> 4) * 8;
#pragma unroll
    for (int j = 0; j < 8; j++) dst[j] = f2bf(src[j]);
  }
}

// ---- Prologue 2: bias, scal, zero padded counters ---------------------------
extern "C" __global__ void prologue2(const float* __restrict__ b_ih,
                                     const float* __restrict__ b_hh,
                                     const float* __restrict__ ln2g,
                                     const float* __restrict__ ln2b,
                                     const float* __restrict__ posW,
                                     float* __restrict__ biasv,
                                     float* __restrict__ scal,
                                     int* __restrict__ ctr) {
  int t = threadIdx.x;  // 256
#pragma unroll
  for (int k2 = 0; k2 < 4; k2++) {
    int n = t * 4 + k2;
    biasv[n] = b_ih[n] + b_hh[n];
  }
  if (t < 64) ctr[t * 64] = 0;
  __shared__ float red[256][4];
  float g = ln2g[t], b = ln2b[t], p0 = posW[t], p1 = posW[256 + t];
  red[t][0] = b * p0;
  red[t][1] = b * p1;
  red[t][2] = g * p0;
  red[t][3] = g * p1;
  __syncthreads();
  for (int s = 128; s > 0; s >>= 1) {
    if (t < s) {
#pragma unroll
      for (int v = 0; v < 4; v++) red[t][v] += red[t + s][v];
    }
    __syncthreads();
  }
  if (t == 0) {
#pragma unroll
    for (int v = 0; v < 4; v++) scal[v] = red[0][v];
  }
}

// ---- Main persistent decoder ------------------------------------------------
extern "C" __global__ __launch_bounds__(512, 2) void decoder_main(
    const float* __restrict__ lpr, const float* __restrict__ h0,
    const float* __restrict__ c0, const float* __restrict__ embW,
    const float* __restrict__ embB, const float* __restrict__ ln1g,
    const float* __restrict__ ln1b, const float* __restrict__ posW,
    const float* __restrict__ posB, const float* __restrict__ ln2g,
    const unsigned short* __restrict__ ws_w,
    unsigned short* __restrict__ hbuf,  // h exchange
    float* __restrict__ sbuf,           // stats exchange
    const float* __restrict__ biasv, const float* __restrict__ scal,
    int* __restrict__ ctr, float* __restrict__ out) {
  __shared__ unsigned short w_lds[4 * 16 * 512];   // 64 KB, kc 0..3
  __shared__ unsigned short h_stage[8 * 8 * 512];  // 64 KB [Tl8][kc8][512]
  __shared__ unsigned short xh[16 * 512];          // 16 KB x-frags / h_out
  __shared__ float partials[128 * 16];             // 8 KB [pl][uw*4+c]
  __shared__ float statl[384 * 4];                 // 6 KB partner stats
  __shared__ float n01[128][2];                    // 1 KB

  const int bid = blockIdx.x;
  const int pg = bid >> 2, ug = bid & 3;
  const int tid = threadIdx.x;
  const int w = tid >> 6, l = tid & 63;
  const int uw = w & 3, pw = w >> 2;
  const int q = l >> 4, li = l & 15;
  const int P0 = pg * 128;
  const int loff = l * 8;
  const int u = ug * 64 + uw * 16 + li;

  // ---- weights: LDS part (kc 0..3) ----
  {
    const unsigned short* src = ws_w + (size_t)ug * 81920;
#pragma unroll
    for (int it = 0; it < 8; it++) {
      int f = tid + it * 512;
      *(short8*)(w_lds + f * 8) = *(const short8*)(src + f * 8);
    }
  }
  // ---- weights: register part (kc 4..9) ----
  short8 wr[6][4];
#pragma unroll
  for (int kk = 0; kk < 6; kk++)
#pragma unroll
    for (int g = 0; g < 4; g++)
      wr[kk][g] = *(const short8*)(ws_w + (size_t)ug * 81920 +
                                   ((kk + 4) * 16 + g * 4 + uw) * 512 + loff);

  const float K0 = scal[0], K1 = scal[1], SP0 = scal[2], SP1 = scal[3];
  const float pb0 = posB[0], pb1 = posB[1];
  const float g10 = ln1g[0], g11 = ln1g[1], b10 = ln1b[0], b11 = ln1b[1];

  float bias_r[4];
#pragma unroll
  for (int g = 0; g < 4; g++) bias_r[g] = biasv[g * 256 + u];
  float Pp0, Pp1;
  {
    float gg = ln2g[u];
    Pp0 = gg * posW[u];
    Pp1 = gg * posW[256 + u];
  }

  // ---- c0 ----
  f32x4 c_r[4];
#pragma unroll
  for (int mt = 0; mt < 4; mt++)
#pragma unroll
    for (int r = 0; r < 4; r++)
      c_r[mt][r] = c0[(size_t)(P0 + pw * 64 + mt * 16 + q * 4 + r) * 256 + u];

  // ---- h0 -> h_stage ----
#pragma unroll
  for (int it = 0; it < 8; it++) {
    int f = tid + it * 512;  // 0..4095
    int ll = f & 63, kc = (f >> 6) & 7, Tl = f >> 9;
    const float* src =
        h0 + (size_t)(P0 + Tl * 16 + (ll & 15)) * 256 + kc * 32 + (ll >> 4) * 8;
    float tf[8];
    *(float4*)&tf[0] = *(const float4*)(src);
    *(float4*)&tf[4] = *(const float4*)(src + 4);
    short8 sv;
#pragma unroll
    for (int j = 0; j < 8; j++) sv[j] = (short)f2bf(tf[j]);
    *(short8*)(h_stage + f * 8) = sv;
  }

  // ---- n01 from lpr ----
  if (tid < 128) {
    float r0 = lpr[(P0 + tid) * 2], r1 = lpr[(P0 + tid) * 2 + 1];
    float d = 0.5f * (r0 - r1);
    float rs = rsqrtf(d * d + 1e-5f);
    n01[tid][0] = d * rs * g10 + b10;
    n01[tid][1] = -d * rs * g11 + b11;
  }
  __syncthreads();

  // ---- x0 = embed(n01) into xh ----
  {
    const int pc = tid >> 2, s4 = tid & 3;
    float n0 = n01[pc][0], n1 = n01[pc][1];
    int Tl = pc >> 4, row = pc & 15;
#pragma unroll
    for (int jj = 0; jj < 16; jj++) {
      int k = s4 * 16 + jj;
      float e = n0 * embW[k * 2] + n1 * embW[k * 2 + 1] + embB[k];
      e = e > 0.f ? e : 0.01f * e;
      xh[(Tl * 2 + (k >> 5)) * 512 + (row + 16 * ((k & 31) >> 3)) * 8 + (k & 7)] =
          f2bf(e);
    }
  }
  __syncthreads();

  i32x4* hb4 = (i32x4*)hbuf;
  i32x4* sb4 = (i32x4*)sbuf;

  for (int st = 0; st < 30; st++) {
    const size_t pbase = (size_t)(st & 1) * 262144;  // h parity (i32x4 units)
    const size_t sbase = (size_t)(st & 1) * 32768;   // stats parity

    f32x4 acc[4][4];
#pragma unroll
    for (int g = 0; g < 4; g++)
#pragma unroll
      for (int mt = 0; mt < 4; mt++)
        acc[g][mt] = (f32x4){bias_r[g], bias_r[g], bias_r[g], bias_r[g]};

    // ---- x phase ----
#pragma unroll
    for (int kc2 = 0; kc2 < 2; kc2++) {
      short8 ax[4];
#pragma unroll
      for (int mt = 0; mt < 4; mt++)
        ax[mt] = *(const short8*)(xh + ((pw * 4 + mt) * 2 + kc2) * 512 + loff);
#pragma unroll
      for (int g = 0; g < 4; g++) {
        short8 b = *(const short8*)(w_lds + (kc2 * 16 + g * 4 + uw) * 512 + loff);
#pragma unroll
        for (int mt = 0; mt < 4; mt++)
          acc[g][mt] = mfma16(ax[mt], b, acc[g][mt]);
      }
    }
    // ---- h phase ----
#pragma unroll
    for (int kc = 0; kc < 8; kc++) {
      short8 a[4];
#pragma unroll
      for (int mt = 0; mt < 4; mt++)
        a[mt] = *(const short8*)(h_stage + ((pw * 4 + mt) * 8 + kc) * 512 + loff);
      if (kc < 2) {
#pragma unroll
        for (int g = 0; g < 4; g++) {
          short8 b =
              *(const short8*)(w_lds + ((kc + 2) * 16 + g * 4 + uw) * 512 + loff);
#pragma unroll
          for (int mt = 0; mt < 4; mt++)
            acc[g][mt] = mfma16(a[mt], b, acc[g][mt]);
        }
      } else {
#pragma unroll
        for (int g = 0; g < 4; g++)
#pragma unroll
          for (int mt = 0; mt < 4; mt++)
            acc[g][mt] = mfma16(a[mt], wr[kc - 2][g], acc[g][mt]);
      }
    }
    __syncthreads();  // #1: xh / h_stage reads done

    // ---- cell: c,h update; own h frags -> xh overlay; stats partials ----
#pragma unroll
    for (int mt = 0; mt < 4; mt++) {
      float sh[4], sh2[4], sA[4], sB[4];
#pragma unroll
      for (int r = 0; r < 4; r++) {
        float iv = sigm(acc[0][mt][r]);
        float fv = sigm(acc[1][mt][r]);
        float gv = tanh_(acc[2][mt][r]);
        float ov = sigm(acc[3][mt][r]);
        float cc = fv * c_r[mt][r] + iv * gv;
        c_r[mt][r] = cc;
        float hv = ov * tanh_(cc);
        xh[((pw * 4 + mt) * 2 + (uw >> 1)) * 512 +
           ((q * 4 + r) + 16 * ((uw & 1) * 2 + (li >> 3))) * 8 + (li & 7)] =
            f2bf(hv);
        sh[r] = hv;
        sh2[r] = hv * hv;
        sA[r] = hv * Pp0;
        sB[r] = hv * Pp1;
      }
#pragma unroll
      for (int mask = 1; mask <= 8; mask <<= 1) {
#pragma unroll
        for (int r = 0; r < 4; r++) {
          sh[r] += __shfl_xor(sh[r], mask, 64);
          sh2[r] += __shfl_xor(sh2[r], mask, 64);
          sA[r] += __shfl_xor(sA[r], mask, 64);
          sB[r] += __shfl_xor(sB[r], mask, 64);
        }
      }
      if (li == 0) {
#pragma unroll
        for (int r = 0; r < 4; r++)
          *(f32x4*)(partials + (pw * 64 + mt * 16 + q * 4 + r) * 16 + uw * 4) =
              (f32x4){sh[r], sh2[r], sA[r], sB[r]};
      }
    }
    __syncthreads();  // #2: xh own-h + partials complete

    // ---- own h -> h_stage (LDS) + sc-store; own stats combine + sc-store ----
    f32x4 sown = (f32x4){0.f, 0.f, 0.f, 0.f};
    {
      const i32x4* xh4 = (const i32x4*)xh;
      i32x4* hs4 = (i32x4*)h_stage;
#pragma unroll
      for (int it = 0; it < 2; it++) {
        int f = tid + it * 512;  // 0..1023
        int s = f & 63, c = f >> 6, Tl = c >> 1, kcl = c & 1;
        i32x4 v = xh4[f];
        hs4[(Tl * 8 + 2 * ug + kcl) * 64 + s] = v;
        sc_store16(hb4 + pbase +
                       (((size_t)(pg * 8 + Tl)) * 8 + 2 * ug + kcl) * 64 + s,
                   v);
      }
      if (tid < 128) {
        f32x4 sv = *(const f32x4*)(partials + tid * 16);
#pragma unroll
        for (int uu = 1; uu < 4; uu++) {
          f32x4 t2 = *(const f32x4*)(partials + tid * 16 + uu * 4);
          sv.x += t2.x; sv.y += t2.y; sv.z += t2.z; sv.w += t2.w;
        }
        sown = sv;
        sc_store16(sb4 + sbase + ((size_t)pg * 4 + ug) * 128 + tid,
                   __builtin_bit_cast(i32x4, sv));
      }
      drain_vm();
    }
    __syncthreads();  // #3: all stores drained block-wide

    if (tid == 0) {
      __hip_atomic_fetch_add(ctr + pg * 64, 1, __ATOMIC_RELAXED,
                             __HIP_MEMORY_SCOPE_AGENT);
      int target = 4 * (st + 1);
      while (__hip_atomic_load(ctr + pg * 64, __ATOMIC_RELAXED,
                               __HIP_MEMORY_SCOPE_AGENT) < target)
        __builtin_amdgcn_s_sleep(1);
    }
    __syncthreads();  // #4: partners' h + stats visible

    // ---- ONE batched load: 6 partner-h + 1 partner-stats ----
    {
      const i32x4* ps[7];
      int Tls[6], kcs[6], ss[6];
#pragma unroll
      for (int it = 0; it < 6; it++) {
        int f = tid + it * 512;      // 0..3071
        int s = f & 63, x = f >> 6;  // 0..47
        int Tl = x / 6, j = x - Tl * 6;
        int kc = j + (j >= 2 * ug ? 2 : 0);
        Tls[it] = Tl; kcs[it] = kc; ss[it] = s;
        ps[it] = hb4 + pbase + (((size_t)(pg * 8 + Tl)) * 8 + kc) * 64 + s;
      }
      int spi = tid >> 7, sped = tid & 127;
      int pu = (spi < 3) ? (spi + (spi >= ug ? 1 : 0)) : ug;  // tid>=384 dummy
      ps[6] = sb4 + sbase + ((size_t)pg * 4 + pu) * 128 + sped;

      i32x4 r0, r1, r2, r3, r4, r5, r6;
      batch_load7(ps[0], ps[1], ps[2], ps[3], ps[4], ps[5], ps[6], r0, r1, r2,
                  r3, r4, r5, r6);
      i32x4* hs4 = (i32x4*)h_stage;
      hs4[(Tls[0] * 8 + kcs[0]) * 64 + ss[0]] = r0;
      hs4[(Tls[1] * 8 + kcs[1]) * 64 + ss[1]] = r1;
      hs4[(Tls[2] * 8 + kcs[2]) * 64 + ss[2]] = r2;
      hs4[(Tls[3] * 8 + kcs[3]) * 64 + ss[3]] = r3;
      hs4[(Tls[4] * 8 + kcs[4]) * 64 + ss[4]] = r4;
      hs4[(Tls[5] * 8 + kcs[5]) * 64 + ss[5]] = r5;
      if (tid < 384) *(i32x4*)(statl + tid * 4) = r6;
    }
    __syncthreads();  // #5: h_stage full; statl ready

    // ---- rel + out + n01 (own stats in regs, partners from statl) ----
    if (tid < 128) {
      float S = sown.x, S2 = sown.y, D0 = sown.z, D1 = sown.w;
#pragma unroll
      for (int p = 0; p < 3; p++) {
        f32x4 v = *(const f32x4*)(statl + (p * 128 + tid) * 4);
        S += v.x; S2 += v.y; D0 += v.z; D1 += v.w;
      }
      float mu = S * (1.0f / 256.0f);
      float var = S2 * (1.0f / 256.0f) - mu * mu;
      float rsig = rsqrtf(var + 1e-5f);
      float rel0 = sigm(rsig * (D0 - mu * SP0) + K0 + pb0);
      float rel1 = sigm(rsig * (D1 - mu * SP1) + K1 + pb1);
      if (ug == 0)
        *(float2*)(out + (size_t)st * 16384 + (P0 + tid) * 2) =
            make_float2(rel0, rel1);
      float d = 0.5f * (rel0 - rel1);
      float rs = rsqrtf(d * d + 1e-5f);
      n01[tid][0] = d * rs * g10 + b10;
      n01[tid][1] = -d * rs * g11 + b11;
    }
    __syncthreads();  // #6: n01 ready

    if (st < 29) {
      const int pc = tid >> 2, s4 = tid & 3;
      float n0 = n01[pc][0], n1 = n01[pc][1];
      int Tl = pc >> 4, row = pc & 15;
#pragma unroll
      for (int jj = 0; jj < 16; jj++) {
        int k = s4 * 16 + jj;
        float e = n0 * embW[k * 2] + n1 * embW[k * 2 + 1] + embB[k];
        e = e > 0.f ? e : 0.01f * e;
        xh[(Tl * 2 + (k >> 5)) * 512 + (row + 16 * ((k & 31) >> 3)) * 8 +
           (k & 7)] = f2bf(e);
      }
    }
    __syncthreads();  // #7: xh ready for next step
  }
}

extern "C" void kernel_launch(void* const* d_in, const int* in_sizes, int n_in,
                              void* d_out, int out_size, void* d_ws,
                              size_t ws_size, hipStream_t stream) {
  (void)in_sizes; (void)n_in; (void)out_size; (void)ws_size;
  const float* lpr  = (const float*)d_in[1];
  const float* h0   = (const float*)d_in[2];
  const float* c0   = (const float*)d_in[3];
  const float* Wih  = (const float*)d_in[4];
  const float* Whh  = (const float*)d_in[5];
  const float* b_ih = (const float*)d_in[6];
  const float* b_hh = (const float*)d_in[7];
  const float* embW = (const float*)d_in[8];
  const float* embB = (const float*)d_in[9];
  const float* ln1g = (const float*)d_in[10];
  const float* ln1b = (const float*)d_in[11];
  const float* posW = (const float*)d_in[12];
  const float* posB = (const float*)d_in[13];
  const float* ln2g = (const float*)d_in[14];
  const float* ln2b = (const float*)d_in[15];

  char* ws = (char*)d_ws;
  unsigned short* ws_w = (unsigned short*)(ws + WS_W);
  unsigned short* hbuf = (unsigned short*)(ws + WS_HBUF);
  float* sbufp  = (float*)(ws + WS_SBUF);
  float* biasv  = (float*)(ws + WS_BIAS);
  float* scal   = (float*)(ws + WS_SCAL);
  int*   ctr    = (int*)(ws + WS_CTR);

  shuffle_weights<<<dim3(160), dim3(256), 0, stream>>>(Wih, Whh, ws_w);
  prologue2<<<dim3(1), dim3(256), 0, stream>>>(b_ih, b_hh, ln2g, ln2b, posW,
                                               biasv, scal, ctr);
  decoder_main<<<dim3(256), dim3(512), 0, stream>>>(
      lpr, h0, c0, embW, embB, ln1g, ln1b, posW, posB, ln2g, ws_w, hbuf,
      sbufp, biasv, scal, ctr, (float*)d_out);
}

// Round 9
// 545.075 us; speedup vs baseline: 1.3703x; 1.3703x over previous
//
#include <hip/hip_runtime.h>

// DecoderLSTM R9: 2-way unit partition. 256 blocks = 128 ped-groups x 2
// unit-groups; block = 64 peds x 128 units. Weights 320 KB/block: 96 KB LDS
// (kc 0..2) + 112 VGPRs/lane (kc 3..9), loaded ONCE. Exchange per step:
// own-h 16 KB store + partner-h 16 KB load + 1 KB stats, all 16B sc0sc1
// batched asm (in-asm waitcnt). ~2176 coherent ops/block-step (0.47x R8).

typedef float  f32x4  __attribute__((ext_vector_type(4)));
typedef short  short8 __attribute__((ext_vector_type(8)));
typedef __bf16 bf16x8 __attribute__((ext_vector_type(8)));
typedef int    i32x4  __attribute__((ext_vector_type(4)));

#define WS_W     0                      // 640 KB (2 ug x 320 KB)
#define WS_HBUF  (640 * 1024)           // 8 MB: [2][128pg][2ug][16c][64] i32x4
#define WS_SBUF  (WS_HBUF + 8388608)    // 512 KB: [2][128][2][64] i32x4
#define WS_BIAS  (WS_SBUF + 524288)     // 4 KB
#define WS_SCAL  (WS_BIAS + 4096)       // 64 B
#define WS_CTR   (WS_SCAL + 64)         // 128 * 256 B

__device__ __forceinline__ unsigned short f2bf(float f) {
  unsigned int u = __float_as_uint(f);
  u += 0x7FFFu + ((u >> 16) & 1u);  // RNE
  return (unsigned short)(u >> 16);
}
__device__ __forceinline__ float sigm(float x) {
  return __builtin_amdgcn_rcpf(1.0f + __expf(-x));
}
__device__ __forceinline__ float tanh_(float x) {
  float ax = fabsf(x);
  float t = __expf(-2.0f * ax);
  float r = (1.0f - t) * __builtin_amdgcn_rcpf(1.0f + t);
  return x >= 0.0f ? r : -r;
}
__device__ __forceinline__ f32x4 mfma16(short8 a, short8 b, f32x4 c) {
  return __builtin_amdgcn_mfma_f32_16x16x32_bf16(
      __builtin_bit_cast(bf16x8, a), __builtin_bit_cast(bf16x8, b), c, 0, 0, 0);
}
__device__ __forceinline__ void sc_store16(void* p, i32x4 v) {
  asm volatile("global_store_dwordx4 %0, %1, off sc0 sc1" ::"v"(p), "v"(v)
               : "memory");
}
__device__ __forceinline__ void drain_vm() {
  asm volatile("s_waitcnt vmcnt(0)" ::: "memory");
}
// 3 coherent 16B loads, results valid at asm exit (waitcnt inside).
__device__ __forceinline__ void batch_load3(const i32x4* p0, const i32x4* p1,
                                            const i32x4* p2, i32x4& r0,
                                            i32x4& r1, i32x4& r2) {
  asm volatile(
      "global_load_dwordx4 %0, %3, off sc0 sc1\n\t"
      "global_load_dwordx4 %1, %4, off sc0 sc1\n\t"
      "global_load_dwordx4 %2, %5, off sc0 sc1\n\t"
      "s_waitcnt vmcnt(0)"
      : "=&v"(r0), "=&v"(r1), "=&v"(r2)
      : "v"(p0), "v"(p1), "v"(p2)
      : "memory");
}

// ---- Prologue 1: weights -> B-frag bf16 ------------------------------------
// flat idx: (((ug*10 + kc)*8 + w)*4 + g)*512 + l*8 + j
// row = g*256 + ug*128 + w*16 + (l&15); kc<2: Wih col kc*32+(l>>4)*8;
// kc>=2: Whh col (kc-2)*32+(l>>4)*8
extern "C" __global__ void shuffle_weights(const float* __restrict__ Wih,
                                           const float* __restrict__ Whh,
                                           unsigned short* __restrict__ ws_w) {
  int t = blockIdx.x * 256 + threadIdx.x;  // 0..40959
  if (t >= 40960) return;
  int l = t & 63;
  int g = (t >> 6) & 3;
  int w8 = (t >> 8) & 7;
  int y = t >> 11;  // ug*10 + kc
  int kc = y % 10;
  int ug = y / 10;
  int row = g * 256 + ug * 128 + w8 * 16 + (l & 15);
  unsigned short* dst = ws_w + (size_t)t * 8;
  if (kc < 2) {
    const float* src = Wih + row * 64 + kc * 32 + (l >> 4) * 8;
#pragma unroll
    for (int j = 0; j < 8; j++) dst[j] = f2bf(src[j]);
  } else {
    const float* src = Whh + row * 256 + (kc - 2) * 32 + (l >> 4) * 8;
#pragma unroll
    for (int j = 0; j < 8; j++) dst[j] = f2bf(src[j]);
  }
}

// ---- Prologue 2: bias, scal, zero padded counters ---------------------------
extern "C" __global__ void prologue2(const float* __restrict__ b_ih,
                                     const float* __restrict__ b_hh,
                                     const float* __restrict__ ln2g,
                                     const float* __restrict__ ln2b,
                                     const float* __restrict__ posW,
                                     float* __restrict__ biasv,
                                     float* __restrict__ scal,
                                     int* __restrict__ ctr) {
  int t = threadIdx.x;  // 256
#pragma unroll
  for (int k2 = 0; k2 < 4; k2++) {
    int n = t * 4 + k2;
    biasv[n] = b_ih[n] + b_hh[n];
  }
  if (t < 128) ctr[t * 64] = 0;
  __shared__ float red[256][4];
  float g = ln2g[t], b = ln2b[t], p0 = posW[t], p1 = posW[256 + t];
  red[t][0] = b * p0;
  red[t][1] = b * p1;
  red[t][2] = g * p0;
  red[t][3] = g * p1;
  __syncthreads();
  for (int s = 128; s > 0; s >>= 1) {
    if (t < s) {
#pragma unroll
      for (int v = 0; v < 4; v++) red[t][v] += red[t + s][v];
    }
    __syncthreads();
  }
  if (t == 0) {
#pragma unroll
    for (int v = 0; v < 4; v++) scal[v] = red[0][v];
  }
}

// ---- Main persistent decoder ------------------------------------------------
extern "C" __global__ __launch_bounds__(512, 2) void decoder_main(
    const float* __restrict__ lpr, const float* __restrict__ h0,
    const float* __restrict__ c0, const float* __restrict__ embW,
    const float* __restrict__ embB, const float* __restrict__ ln1g,
    const float* __restrict__ ln1b, const float* __restrict__ posW,
    const float* __restrict__ posB, const float* __restrict__ ln2g,
    const unsigned short* __restrict__ ws_w,
    unsigned short* __restrict__ hbuf,  // h exchange
    float* __restrict__ sbuf,           // stats exchange
    const float* __restrict__ biasv, const float* __restrict__ scal,
    int* __restrict__ ctr, float* __restrict__ out) {
  __shared__ unsigned short w_lds[3 * 8 * 4 * 512];  // 96 KB, kc 0..2
  __shared__ unsigned short h_stage[4 * 8 * 512];    // 32 KB [Tl4][kc8][512]
  __shared__ unsigned short xh[4 * 2 * 512];         // 8 KB x A-frags
  __shared__ float partials[64 * 8 * 4];             // 8 KB [ped][w] f32x4
  __shared__ float statl[64 * 4];                    // 1 KB partner stats
  __shared__ float n01[64][2];                       // 512 B

  const int bid = blockIdx.x;
  const int pg = bid >> 1, ug = bid & 1;
  const int tid = threadIdx.x;
  const int w = tid >> 6, l = tid & 63;
  const int q = l >> 4, li = l & 15;
  const int P0 = pg * 64;
  const int loff = l * 8;
  const int u = ug * 128 + w * 16 + li;

  // ---- weights: LDS part (kc 0..2) ----
  {
    const unsigned short* src = ws_w + (size_t)ug * 163840;
#pragma unroll
    for (int it = 0; it < 12; it++) {
      int f = tid + it * 512;
      *(short8*)(w_lds + f * 8) = *(const short8*)(src + f * 8);
    }
  }
  // ---- weights: register part (kc 3..9) ----
  short8 wr[7][4];
#pragma unroll
  for (int kk = 0; kk < 7; kk++)
#pragma unroll
    for (int g = 0; g < 4; g++)
      wr[kk][g] = *(const short8*)(ws_w + (size_t)ug * 163840 +
                                   (((kk + 3) * 8 + w) * 4 + g) * 512 + loff);

  const float K0 = scal[0], K1 = scal[1], SP0 = scal[2], SP1 = scal[3];
  const float pb0 = posB[0], pb1 = posB[1];
  const float g10 = ln1g[0], g11 = ln1g[1], b10 = ln1b[0], b11 = ln1b[1];

  float bias_r[4];
#pragma unroll
  for (int g = 0; g < 4; g++) bias_r[g] = biasv[g * 256 + u];
  float Pp0, Pp1;
  {
    float gg = ln2g[u];
    Pp0 = gg * posW[u];
    Pp1 = gg * posW[256 + u];
  }

  // ---- c0 ----
  f32x4 c_r[4];
#pragma unroll
  for (int mt = 0; mt < 4; mt++)
#pragma unroll
    for (int r = 0; r < 4; r++)
      c_r[mt][r] = c0[(size_t)(P0 + mt * 16 + q * 4 + r) * 256 + u];

  // ---- h0 -> h_stage (full 256 units for 64 peds) ----
#pragma unroll
  for (int it = 0; it < 4; it++) {
    int f = tid + it * 512;  // 0..2047 short8-slots
    int ll = f & 63, kc = (f >> 6) & 7, Tl = f >> 9;
    const float* src =
        h0 + (size_t)(P0 + Tl * 16 + (ll & 15)) * 256 + kc * 32 + (ll >> 4) * 8;
    float tf[8];
    *(float4*)&tf[0] = *(const float4*)(src);
    *(float4*)&tf[4] = *(const float4*)(src + 4);
    short8 sv;
#pragma unroll
    for (int j = 0; j < 8; j++) sv[j] = (short)f2bf(tf[j]);
    *(short8*)(h_stage + f * 8) = sv;
  }

  // ---- n01 from lpr ----
  if (tid < 64) {
    float r0 = lpr[(P0 + tid) * 2], r1 = lpr[(P0 + tid) * 2 + 1];
    float d = 0.5f * (r0 - r1);
    float rs = rsqrtf(d * d + 1e-5f);
    n01[tid][0] = d * rs * g10 + b10;
    n01[tid][1] = -d * rs * g11 + b11;
  }
  __syncthreads();

  // ---- x0 = embed(n01) into xh (8 threads/ped, 8 k each) ----
  {
    const int pc = tid >> 3, s8 = tid & 7;
    float n0 = n01[pc][0], n1 = n01[pc][1];
    int Tl = pc >> 4, row = pc & 15;
#pragma unroll
    for (int jj = 0; jj < 8; jj++) {
      int k = s8 * 8 + jj;
      float e = n0 * embW[k * 2] + n1 * embW[k * 2 + 1] + embB[k];
      e = e > 0.f ? e : 0.01f * e;
      xh[(Tl * 2 + (k >> 5)) * 512 + (row + 16 * ((k & 31) >> 3)) * 8 + (k & 7)] =
          f2bf(e);
    }
  }
  __syncthreads();

  i32x4* hb4 = (i32x4*)hbuf;
  i32x4* sb4 = (i32x4*)sbuf;
  i32x4* hs4 = (i32x4*)h_stage;
  const size_t own_base = ((size_t)pg * 2 + ug) * 1024;
  const size_t par_base = ((size_t)pg * 2 + (ug ^ 1)) * 1024;
  const size_t sown_base = ((size_t)pg * 2 + ug) * 64;
  const size_t spar_base = ((size_t)pg * 2 + (ug ^ 1)) * 64;

  for (int st = 0; st < 30; st++) {
    const size_t pbase = (size_t)(st & 1) * 262144;  // hbuf parity (i32x4)
    const size_t sbase = (size_t)(st & 1) * 16384;   // sbuf parity (i32x4)

    f32x4 acc[4][4];
#pragma unroll
    for (int g = 0; g < 4; g++)
#pragma unroll
      for (int mt = 0; mt < 4; mt++)
        acc[g][mt] = (f32x4){bias_r[g], bias_r[g], bias_r[g], bias_r[g]};

    // ---- x phase (B from LDS kc 0,1) ----
#pragma unroll
    for (int kc2 = 0; kc2 < 2; kc2++) {
      short8 ax[4];
#pragma unroll
      for (int mt = 0; mt < 4; mt++)
        ax[mt] = *(const short8*)(xh + (mt * 2 + kc2) * 512 + loff);
#pragma unroll
      for (int g = 0; g < 4; g++) {
        short8 b =
            *(const short8*)(w_lds + ((kc2 * 8 + w) * 4 + g) * 512 + loff);
#pragma unroll
        for (int mt = 0; mt < 4; mt++)
          acc[g][mt] = mfma16(ax[mt], b, acc[g][mt]);
      }
    }
    // ---- h phase (kc 0 from LDS, kc 1..7 from regs) ----
#pragma unroll
    for (int kc = 0; kc < 8; kc++) {
      short8 a[4];
#pragma unroll
      for (int mt = 0; mt < 4; mt++)
        a[mt] = *(const short8*)(h_stage + (mt * 8 + kc) * 512 + loff);
      if (kc == 0) {
#pragma unroll
        for (int g = 0; g < 4; g++) {
          short8 b =
              *(const short8*)(w_lds + ((2 * 8 + w) * 4 + g) * 512 + loff);
#pragma unroll
          for (int mt = 0; mt < 4; mt++)
            acc[g][mt] = mfma16(a[mt], b, acc[g][mt]);
        }
      } else {
#pragma unroll
        for (int g = 0; g < 4; g++)
#pragma unroll
          for (int mt = 0; mt < 4; mt++)
            acc[g][mt] = mfma16(a[mt], wr[kc - 1][g], acc[g][mt]);
      }
    }
    __syncthreads();  // #1: all xh / h_stage reads done

    // ---- cell: write own h A-frags DIRECTLY into h_stage; stats ----
#pragma unroll
    for (int mt = 0; mt < 4; mt++) {
      float sh[4], sh2[4], sA[4], sB[4];
#pragma unroll
      for (int r = 0; r < 4; r++) {
        float iv = sigm(acc[0][mt][r]);
        float fv = sigm(acc[1][mt][r]);
        float gv = tanh_(acc[2][mt][r]);
        float ov = sigm(acc[3][mt][r]);
        float cc = fv * c_r[mt][r] + iv * gv;
        c_r[mt][r] = cc;
        float hv = ov * tanh_(cc);
        // own unit u_loc = w*16+li -> kc = ug*4 + (w>>1), ksub = (w&1)*16+li
        h_stage[(mt * 8 + ug * 4 + (w >> 1)) * 512 +
                ((q * 4 + r) + 16 * ((w & 1) * 2 + (li >> 3))) * 8 + (li & 7)] =
            f2bf(hv);
        sh[r] = hv;
        sh2[r] = hv * hv;
        sA[r] = hv * Pp0;
        sB[r] = hv * Pp1;
      }
#pragma unroll
      for (int mask = 1; mask <= 8; mask <<= 1) {
#pragma unroll
        for (int r = 0; r < 4; r++) {
          sh[r] += __shfl_xor(sh[r], mask, 64);
          sh2[r] += __shfl_xor(sh2[r], mask, 64);
          sA[r] += __shfl_xor(sA[r], mask, 64);
          sB[r] += __shfl_xor(sB[r], mask, 64);
        }
      }
      if (li == 0) {
#pragma unroll
        for (int r = 0; r < 4; r++)
          *(f32x4*)(partials + ((mt * 16 + q * 4 + r) * 8 + w) * 4) =
              (f32x4){sh[r], sh2[r], sA[r], sB[r]};
      }
    }
    __syncthreads();  // #2: own-h in h_stage + partials complete

    // ---- own h sc-store (from h_stage) + stats combine/sc-store ----
    f32x4 sown = (f32x4){0.f, 0.f, 0.f, 0.f};
    if (st < 29) {
#pragma unroll
      for (int it = 0; it < 2; it++) {
        int f = tid + it * 512;  // 0..1023
        int c = f >> 6, rr = f & 63;
        int mt = c >> 2, kcl = c & 3;
        i32x4 v = hs4[(mt * 8 + ug * 4 + kcl) * 64 + rr];
        sc_store16(hb4 + pbase + own_base + f, v);
      }
    }
    if (tid < 64) {
      f32x4 sv = *(const f32x4*)(partials + tid * 32);
#pragma unroll
      for (int ww = 1; ww < 8; ww++) {
        f32x4 t2 = *(const f32x4*)(partials + (tid * 8 + ww) * 4);
        sv.x += t2.x; sv.y += t2.y; sv.z += t2.z; sv.w += t2.w;
      }
      sown = sv;
      sc_store16(sb4 + sbase + sown_base + tid, __builtin_bit_cast(i32x4, sv));
    }
    drain_vm();
    __syncthreads();  // #3: all stores drained block-wide

    if (tid == 0) {
      __hip_atomic_fetch_add(ctr + pg * 64, 1, __ATOMIC_RELAXED,
                             __HIP_MEMORY_SCOPE_AGENT);
      int target = 2 * (st + 1);
      while (__hip_atomic_load(ctr + pg * 64, __ATOMIC_RELAXED,
                               __HIP_MEMORY_SCOPE_AGENT) < target)
        __builtin_amdgcn_s_sleep(1);
    }
    __syncthreads();  // #4: partner h + stats visible

    // ---- ONE batched load: 2 partner-h + 1 partner-stats ----
    {
      const i32x4* p0 = hb4 + pbase + par_base + tid;
      const i32x4* p1 = p0 + 512;
      const i32x4* p2 =
          (tid < 64) ? (sb4 + sbase + spar_base + tid) : p0;
      i32x4 r0, r1, r2;
      batch_load3(p0, p1, p2, r0, r1, r2);
      if (st < 29) {
        int c0i = tid >> 6, rr = tid & 63;
        hs4[((c0i >> 2) * 8 + (ug ^ 1) * 4 + (c0i & 3)) * 64 + rr] = r0;
        int f1 = tid + 512;
        int c1 = f1 >> 6, rr1 = f1 & 63;
        hs4[((c1 >> 2) * 8 + (ug ^ 1) * 4 + (c1 & 3)) * 64 + rr1] = r1;
      }
      if (tid < 64) *(i32x4*)(statl + tid * 4) = __builtin_bit_cast(i32x4, r2);
    }
    __syncthreads();  // #5: h_stage = h_{t+1} full; statl ready

    // ---- rel + out + n01 ----
    if (tid < 64) {
      f32x4 sp = *(const f32x4*)(statl + tid * 4);
      float S = sown.x + sp.x;
      float S2 = sown.y + sp.y;
      float D0 = sown.z + sp.z;
      float D1 = sown.w + sp.w;
      float mu = S * (1.0f / 256.0f);
      float var = S2 * (1.0f / 256.0f) - mu * mu;
      float rsig = rsqrtf(var + 1e-5f);
      float rel0 = sigm(rsig * (D0 - mu * SP0) + K0 + pb0);
      float rel1 = sigm(rsig * (D1 - mu * SP1) + K1 + pb1);
      if (ug == 0)
        *(float2*)(out + (size_t)st * 16384 + (P0 + tid) * 2) =
            make_float2(rel0, rel1);
      float d = 0.5f * (rel0 - rel1);
      float rs = rsqrtf(d * d + 1e-5f);
      n01[tid][0] = d * rs * g10 + b10;
      n01[tid][1] = -d * rs * g11 + b11;
    }
    __syncthreads();  // #6: n01 ready

    if (st < 29) {
      const int pc = tid >> 3, s8 = tid & 7;
      float n0 = n01[pc][0], n1 = n01[pc][1];
      int Tl = pc >> 4, row = pc & 15;
#pragma unroll
      for (int jj = 0; jj < 8; jj++) {
        int k = s8 * 8 + jj;
        float e = n0 * embW[k * 2] + n1 * embW[k * 2 + 1] + embB[k];
        e = e > 0.f ? e : 0.01f * e;
        xh[(Tl * 2 + (k >> 5)) * 512 + (row + 16 * ((k & 31) >> 3)) * 8 +
           (k & 7)] = f2bf(e);
      }
    }
    __syncthreads();  // #7: xh ready for next step
  }
}

extern "C" void kernel_launch(void* const* d_in, const int* in_sizes, int n_in,
                              void* d_out, int out_size, void* d_ws,
                              size_t ws_size, hipStream_t stream) {
  (void)in_sizes; (void)n_in; (void)out_size; (void)ws_size;
  const float* lpr  = (const float*)d_in[1];
  const float* h0   = (const float*)d_in[2];
  const float* c0   = (const float*)d_in[3];
  const float* Wih  = (const float*)d_in[4];
  const float* Whh  = (const float*)d_in[5];
  const float* b_ih = (const float*)d_in[6];
  const float* b_hh = (const float*)d_in[7];
  const float* embW = (const float*)d_in[8];
  const float* embB = (const float*)d_in[9];
  const float* ln1g = (const float*)d_in[10];
  const float* ln1b = (const float*)d_in[11];
  const float* posW = (const float*)d_in[12];
  const float* posB = (const float*)d_in[13];
  const float* ln2g = (const float*)d_in[14];
  const float* ln2b = (const float*)d_in[15];

  char* ws = (char*)d_ws;
  unsigned short* ws_w = (unsigned short*)(ws + WS_W);
  unsigned short* hbuf = (unsigned short*)(ws + WS_HBUF);
  float* sbufp  = (float*)(ws + WS_SBUF);
  float* biasv  = (float*)(ws + WS_BIAS);
  float* scal   = (float*)(ws + WS_SCAL);
  int*   ctr    = (int*)(ws + WS_CTR);

  shuffle_weights<<<dim3(160), dim3(256), 0, stream>>>(Wih, Whh, ws_w);
  prologue2<<<dim3(1), dim3(256), 0, stream>>>(b_ih, b_hh, ln2g, ln2b, posW,
                                               biasv, scal, ctr);
  decoder_main<<<dim3(256), dim3(512), 0, stream>>>(
      lpr, h0, c0, embW, embB, ln1g, ln1b, posW, posB, ln2g, ws_w, hbuf,
      sbufp, biasv, scal, ctr, (float*)d_out);
}